// Round 2
// baseline (885.160 us; speedup 1.0000x reference)
//
#include <hip/hip_runtime.h>
#include <hip/hip_bf16.h>
#include <math.h>

#define DEVINL __device__ __forceinline__

DEVINL float lrelu(float x) { return x > 0.f ? x : 0.2f * x; }

// ---------------- utility kernels ----------------

__global__ void zero_int(int* __restrict__ p, int n) {
    int i = blockIdx.x * 256 + threadIdx.x;
    if (i < n) p[i] = 0;
}

// build src/dst int32 arrays (with self loops appended) + dst histogram
// NOTE: harness delivers integer inputs as int32 ("integer -> const int*")
__global__ void build_edges(const int* __restrict__ ei, int E, int N,
                            int* __restrict__ src, int* __restrict__ dst,
                            int* __restrict__ counts) {
    int e = blockIdx.x * 256 + threadIdx.x;
    int ET = E + N;
    if (e >= ET) return;
    int s, d;
    if (e < E) { s = ei[e]; d = ei[E + e]; }
    else       { s = d = e - E; }
    // defensive clamp (no-op on valid data; prevents faults on bad dtype)
    s = min(max(s, 0), N - 1);
    d = min(max(d, 0), N - 1);
    src[e] = s;
    dst[e] = d;
    atomicAdd(&counts[d], 1);
}

// single-block exclusive scan over counts[N] -> offsets[N+1]
__global__ void scan_offsets(const int* __restrict__ counts, int* __restrict__ offsets, int N) {
    const int T = 1024;
    __shared__ int sums[T];
    int t = threadIdx.x;
    int chunk = (N + T - 1) / T;          // 10 for N=10000
    int base = t * chunk;
    int local[16];                        // chunk <= 16 assumed (N <= 16384)
    int s = 0;
    for (int i = 0; i < chunk; ++i) {
        int v = (base + i < N) ? counts[base + i] : 0;
        local[i] = s;                      // exclusive within chunk
        s += v;
    }
    sums[t] = s;
    __syncthreads();
    for (int d = 1; d < T; d <<= 1) {      // Hillis-Steele inclusive scan
        int v = (t >= d) ? sums[t - d] : 0;
        __syncthreads();
        sums[t] += v;
        __syncthreads();
    }
    int excl = (t == 0) ? 0 : sums[t - 1];
    for (int i = 0; i < chunk; ++i)
        if (base + i < N) offsets[base + i] = excl + local[i];
    if (t == T - 1) offsets[N] = excl + s;
}

__global__ void fill_eids(const int* __restrict__ dst, const int* __restrict__ offsets,
                          int* __restrict__ cursor, int* __restrict__ eids, int ET) {
    int e = blockIdx.x * 256 + threadIdx.x;
    if (e >= ET) return;
    int d = dst[e];
    int pos = offsets[d] + atomicAdd(&cursor[d], 1);
    eids[pos] = e;
}

// ---------------- f32 tiled GEMM: C[M,N] = A[M,K] @ B[K,N] ----------------
// BM=BN=64, BK=16, 256 threads, 4x4 per thread.
__global__ __launch_bounds__(256) void gemm_f32(const float* __restrict__ A,
                                                const float* __restrict__ B,
                                                float* __restrict__ C,
                                                int M, int N, int K) {
    __shared__ float As[16][65];   // transposed A tile, +1 pad
    __shared__ float Bs[16][64];
    int bm = blockIdx.y * 64, bn = blockIdx.x * 64;
    int t = threadIdx.x;
    int tx = t & 15, ty = t >> 4;
    float acc[4][4] = {};
    for (int k0 = 0; k0 < K; k0 += 16) {
        {   // A tile 64x16: thread loads one float4
            int row = t >> 2, cg = (t & 3) * 4;
            int m = bm + row;
            float4 v = make_float4(0.f, 0.f, 0.f, 0.f);
            if (m < M) v = *(const float4*)&A[(size_t)m * K + k0 + cg];
            As[cg + 0][row] = v.x; As[cg + 1][row] = v.y;
            As[cg + 2][row] = v.z; As[cg + 3][row] = v.w;
        }
        {   // B tile 16x64
            int kr = t >> 4, cg = (t & 15) * 4;
            float4 v = *(const float4*)&B[(size_t)(k0 + kr) * N + bn + cg];
            *(float4*)&Bs[kr][cg] = v;
        }
        __syncthreads();
#pragma unroll
        for (int k = 0; k < 16; ++k) {
            float a[4], b[4];
#pragma unroll
            for (int i = 0; i < 4; ++i) a[i] = As[k][ty * 4 + i];
#pragma unroll
            for (int j = 0; j < 4; ++j) b[j] = Bs[k][tx * 4 + j];
#pragma unroll
            for (int i = 0; i < 4; ++i)
#pragma unroll
                for (int j = 0; j < 4; ++j) acc[i][j] += a[i] * b[j];
        }
        __syncthreads();
    }
#pragma unroll
    for (int i = 0; i < 4; ++i) {
        int m = bm + ty * 4 + i;
        if (m < M) {
            float4 v = make_float4(acc[i][0], acc[i][1], acc[i][2], acc[i][3]);
            *(float4*)&C[(size_t)m * N + bn + tx * 4] = v;
        }
    }
}

// ---------------- per-edge attention logits ----------------
// one wave per (edge, head); C = per-head channels (256 or 128)
template <int C>
__global__ __launch_bounds__(256) void edge_logits(const float* __restrict__ xl,
                                                   const float* __restrict__ xr,
                                                   const float* __restrict__ att,
                                                   const int* __restrict__ src,
                                                   const int* __restrict__ dst,
                                                   float* __restrict__ logits, int ET) {
    const int H = 4;
    int wid = (int)((blockIdx.x * (unsigned)blockDim.x + threadIdx.x) >> 6);
    int lane = threadIdx.x & 63;
    if (wid >= ET * H) return;
    int e = wid >> 2, h = wid & 3;
    const int HC = H * C;
    const float* pl = xl + (size_t)src[e] * HC + h * C;
    const float* pr = xr + (size_t)dst[e] * HC + h * C;
    const float* pa = att + h * C;
    float partial = 0.f;
    if (C == 256) {
        float4 l4 = *(const float4*)(pl + lane * 4);
        float4 r4 = *(const float4*)(pr + lane * 4);
        float4 a4 = *(const float4*)(pa + lane * 4);
        partial = a4.x * lrelu(l4.x + r4.x) + a4.y * lrelu(l4.y + r4.y)
                + a4.z * lrelu(l4.z + r4.z) + a4.w * lrelu(l4.w + r4.w);
    } else {
        float2 l2 = *(const float2*)(pl + lane * 2);
        float2 r2 = *(const float2*)(pr + lane * 2);
        float2 a2 = *(const float2*)(pa + lane * 2);
        partial = a2.x * lrelu(l2.x + r2.x) + a2.y * lrelu(l2.y + r2.y);
    }
#pragma unroll
    for (int s = 32; s > 0; s >>= 1) partial += __shfl_xor(partial, s);
    if (lane == 0) logits[e * H + h] = partial;
}

// ---------------- per-node segment softmax + aggregate + head-mean ----------------
// one block per destination node. BLK = H*C/4 threads, each owns one float4.
// ACT: 0 = leaky_relu, 1 = tanh
template <int C, int ACT>
__global__ void segment_agg(const float* __restrict__ xl,
                            const float* __restrict__ logits,
                            const int* __restrict__ src,
                            const int* __restrict__ offsets,
                            const int* __restrict__ eids,
                            const float* __restrict__ bias,
                            float* __restrict__ out, int N) {
    const int H = 4;
    constexpr int HC = H * C;
    constexpr int BLK = HC / 4;
    constexpr int LPH = BLK / 4;   // threads per head in reduction phases
    __shared__ float red[BLK];
    __shared__ float smM[H], smInv[H];
    __shared__ float accLds[HC];
    int n = blockIdx.x;
    int t = threadIdx.x;
    int o0 = offsets[n];
    int deg = offsets[n + 1] - o0;

    // phase A: per-head max of logits
    int h = t & 3, li = t >> 2;
    float pm = -1e30f;
    for (int j = li; j < deg; j += LPH) {
        int eid = eids[o0 + j];
        pm = fmaxf(pm, logits[eid * H + h]);
    }
    red[t] = pm;
    __syncthreads();
    for (int s = LPH >> 1; s > 0; s >>= 1) {
        if (li < s) red[t] = fmaxf(red[t], red[t + s * 4]);
        __syncthreads();
    }
    if (t < H) smM[t] = red[t];
    __syncthreads();

    // phase B: per-head sum of exp
    float m = smM[h];
    float ps = 0.f;
    for (int j = li; j < deg; j += LPH) {
        int eid = eids[o0 + j];
        ps += expf(logits[eid * H + h] - m);
    }
    red[t] = ps;
    __syncthreads();
    for (int s = LPH >> 1; s > 0; s >>= 1) {
        if (li < s) red[t] += red[t + s * 4];
        __syncthreads();
    }
    if (t < H) smInv[t] = 1.0f / red[t];
    __syncthreads();

    // phase C: accumulate alpha * xl[src] over incoming edges
    int myh = (t * 4) / C;
    float mh = smM[myh], invh = smInv[myh];
    float4 acc = make_float4(0.f, 0.f, 0.f, 0.f);
    for (int j = 0; j < deg; ++j) {
        int eid = eids[o0 + j];
        float alpha = expf(logits[eid * H + myh] - mh) * invh;
        int s = src[eid];
        float4 xv = *(const float4*)&xl[(size_t)s * HC + t * 4];
        acc.x += alpha * xv.x; acc.y += alpha * xv.y;
        acc.z += alpha * xv.z; acc.w += alpha * xv.w;
    }
    __syncthreads();
    *(float4*)&accLds[t * 4] = acc;
    __syncthreads();

    // phase D: mean over heads + bias + activation
    if (t < C) {
        float v = 0.f;
#pragma unroll
        for (int hh = 0; hh < H; ++hh) v += accLds[hh * C + t];
        v = v * 0.25f + bias[t];
        if (ACT == 0) v = lrelu(v);
        else          v = tanhf(v);
        out[(size_t)n * C + t] = v;
    }
}

// ---------------- launch ----------------

extern "C" void kernel_launch(void* const* d_in, const int* in_sizes, int n_in,
                              void* d_out, int out_size, void* d_ws, size_t ws_size,
                              hipStream_t stream) {
    const float* x    = (const float*)d_in[0];
    const int*   ei   = (const int*)d_in[1];     // int32 per harness contract
    const float* Wl1  = (const float*)d_in[2];
    const float* Wr1  = (const float*)d_in[3];
    const float* att1 = (const float*)d_in[4];
    const float* b1   = (const float*)d_in[5];
    const float* Wl2  = (const float*)d_in[6];
    const float* Wr2  = (const float*)d_in[7];
    const float* att2 = (const float*)d_in[8];
    const float* b2   = (const float*)d_in[9];
    float* out = (float*)d_out;

    const int IN = 512, HID = 256, OUT = 128, H = 4;
    int N  = in_sizes[0] / IN;
    int E  = in_sizes[1] / 2;
    int ET = E + N;

    // workspace carve (peak ~88 MB with region reuse)
    char* w = (char*)d_ws;
    auto carve = [&](size_t bytes) {
        char* p = w;
        w += (bytes + 255) & ~(size_t)255;
        return (void*)p;
    };
    // region A: layer-1 xl1; reused as layer-2 xl2+xr2 (HID == 2*OUT)
    float* xl1 = (float*)carve((size_t)N * H * HID * 4);
    // region B: layer-1 xr1; reused as h1 after layer-1 logits are done
    float* xr1 = (float*)carve((size_t)N * H * HID * 4);
    float* logits  = (float*)carve((size_t)ET * H * 4);
    int*   src     = (int*)carve((size_t)ET * 4);
    int*   dst     = (int*)carve((size_t)ET * 4);
    int*   counts  = (int*)carve((size_t)N * 4);
    int*   offsets = (int*)carve((size_t)(N + 1) * 4);
    int*   cursor  = (int*)carve((size_t)N * 4);
    int*   eids    = (int*)carve((size_t)ET * 4);
    float* h1  = xr1;                        // written after xr1 last use
    float* xl2 = xl1;                        // written after xl1 last use
    float* xr2 = xl1 + (size_t)N * H * OUT;

    // ---- CSR build (per call; deterministic modulo fp summation order) ----
    zero_int<<<(N + 255) / 256, 256, 0, stream>>>(counts, N);
    build_edges<<<(ET + 255) / 256, 256, 0, stream>>>(ei, E, N, src, dst, counts);
    scan_offsets<<<1, 1024, 0, stream>>>(counts, offsets, N);
    zero_int<<<(N + 255) / 256, 256, 0, stream>>>(cursor, N);
    fill_eids<<<(ET + 255) / 256, 256, 0, stream>>>(dst, offsets, cursor, eids, ET);

    // ---- layer 1: GATv2(512 -> 256, H=4, mean) + leaky_relu ----
    {
        dim3 g((H * HID) / 64, (N + 63) / 64);
        gemm_f32<<<g, 256, 0, stream>>>(x, Wl1, xl1, N, H * HID, IN);
        gemm_f32<<<g, 256, 0, stream>>>(x, Wr1, xr1, N, H * HID, IN);
    }
    edge_logits<256><<<(ET * H + 3) / 4, 256, 0, stream>>>(xl1, xr1, att1, src, dst, logits, ET);
    segment_agg<256, 0><<<N, 256, 0, stream>>>(xl1, logits, src, offsets, eids, b1, h1, N);

    // ---- layer 2: GATv2(256 -> 128, H=4, mean) + tanh ----
    {
        dim3 g((H * OUT) / 64, (N + 63) / 64);
        gemm_f32<<<g, 256, 0, stream>>>(h1, Wl2, xl2, N, H * OUT, HID);
        gemm_f32<<<g, 256, 0, stream>>>(h1, Wr2, xr2, N, H * OUT, HID);
    }
    edge_logits<128><<<(ET * H + 3) / 4, 256, 0, stream>>>(xl2, xr2, att2, src, dst, logits, ET);
    segment_agg<128, 1><<<N, 128, 0, stream>>>(xl2, logits, src, offsets, eids, b2, out, N);
}

// Round 3
// 594.627 us; speedup vs baseline: 1.4886x; 1.4886x over previous
//
#include <hip/hip_runtime.h>
#include <hip/hip_bf16.h>
#include <math.h>

#define DEVINL __device__ __forceinline__

DEVINL float lrelu(float x) { return x > 0.f ? x : 0.2f * x; }

// ---------------- utility kernels ----------------

__global__ void zero_int(int* __restrict__ p, int n) {
    int i = blockIdx.x * 256 + threadIdx.x;
    if (i < n) p[i] = 0;
}

// build src/dst int32 arrays (with self loops appended) + dst histogram
__global__ void build_edges(const int* __restrict__ ei, int E, int N,
                            int* __restrict__ src, int* __restrict__ dst,
                            int* __restrict__ counts) {
    int e = blockIdx.x * 256 + threadIdx.x;
    int ET = E + N;
    if (e >= ET) return;
    int s, d;
    if (e < E) { s = ei[e]; d = ei[E + e]; }
    else       { s = d = e - E; }
    s = min(max(s, 0), N - 1);
    d = min(max(d, 0), N - 1);
    src[e] = s;
    dst[e] = d;
    atomicAdd(&counts[d], 1);
}

// single-block exclusive scan over counts[N] -> offsets[N+1]
__global__ void scan_offsets(const int* __restrict__ counts, int* __restrict__ offsets, int N) {
    const int T = 1024;
    __shared__ int sums[T];
    int t = threadIdx.x;
    int chunk = (N + T - 1) / T;
    int base = t * chunk;
    int local[16];
    int s = 0;
    for (int i = 0; i < chunk; ++i) {
        int v = (base + i < N) ? counts[base + i] : 0;
        local[i] = s;
        s += v;
    }
    sums[t] = s;
    __syncthreads();
    for (int d = 1; d < T; d <<= 1) {
        int v = (t >= d) ? sums[t - d] : 0;
        __syncthreads();
        sums[t] += v;
        __syncthreads();
    }
    int excl = (t == 0) ? 0 : sums[t - 1];
    for (int i = 0; i < chunk; ++i)
        if (base + i < N) offsets[base + i] = excl + local[i];
    if (t == T - 1) offsets[N] = excl + s;
}

// scatter edges into dst-sorted order; store SOURCE node id directly
__global__ void fill_eids(const int* __restrict__ src, const int* __restrict__ dst,
                          const int* __restrict__ offsets,
                          int* __restrict__ cursor, int* __restrict__ esrc, int ET) {
    int e = blockIdx.x * 256 + threadIdx.x;
    if (e >= ET) return;
    int d = dst[e];
    int pos = offsets[d] + atomicAdd(&cursor[d], 1);
    esrc[pos] = src[e];
}

// ---------------- f32 tiled GEMM: C[M,N] = A[M,K] @ B[K,N] ----------------
__global__ __launch_bounds__(256) void gemm_f32(const float* __restrict__ A,
                                                const float* __restrict__ B,
                                                float* __restrict__ C,
                                                int M, int N, int K) {
    __shared__ float As[16][65];
    __shared__ float Bs[16][64];
    int bm = blockIdx.y * 64, bn = blockIdx.x * 64;
    int t = threadIdx.x;
    int tx = t & 15, ty = t >> 4;
    float acc[4][4] = {};
    for (int k0 = 0; k0 < K; k0 += 16) {
        {
            int row = t >> 2, cg = (t & 3) * 4;
            int m = bm + row;
            float4 v = make_float4(0.f, 0.f, 0.f, 0.f);
            if (m < M) v = *(const float4*)&A[(size_t)m * K + k0 + cg];
            As[cg + 0][row] = v.x; As[cg + 1][row] = v.y;
            As[cg + 2][row] = v.z; As[cg + 3][row] = v.w;
        }
        {
            int kr = t >> 4, cg = (t & 15) * 4;
            float4 v = *(const float4*)&B[(size_t)(k0 + kr) * N + bn + cg];
            *(float4*)&Bs[kr][cg] = v;
        }
        __syncthreads();
#pragma unroll
        for (int k = 0; k < 16; ++k) {
            float a[4], b[4];
#pragma unroll
            for (int i = 0; i < 4; ++i) a[i] = As[k][ty * 4 + i];
#pragma unroll
            for (int j = 0; j < 4; ++j) b[j] = Bs[k][tx * 4 + j];
#pragma unroll
            for (int i = 0; i < 4; ++i)
#pragma unroll
                for (int j = 0; j < 4; ++j) acc[i][j] += a[i] * b[j];
        }
        __syncthreads();
    }
#pragma unroll
    for (int i = 0; i < 4; ++i) {
        int m = bm + ty * 4 + i;
        if (m < M) {
            float4 v = make_float4(acc[i][0], acc[i][1], acc[i][2], acc[i][3]);
            *(float4*)&C[(size_t)m * N + bn + tx * 4] = v;
        }
    }
}

// ---------------- fused edge-logits + online segment softmax + aggregate ----------------
// one block per dst node; wave h of 4 handles head h. Lane owns VEC=C/64 channels.
// online softmax: running (m, s, acc) per wave; xl[src] row read exactly once/edge.
// ACT: 0 = leaky_relu, 1 = tanh
template <int C, int ACT>
__global__ __launch_bounds__(256) void fused_agg(const float* __restrict__ xl,
                                                 const float* __restrict__ xr,
                                                 const float* __restrict__ att,
                                                 const int* __restrict__ offsets,
                                                 const int* __restrict__ esrc,
                                                 const float* __restrict__ bias,
                                                 float* __restrict__ out, int N) {
    const int H = 4;
    constexpr int VEC = C / 64;
    constexpr int HC = H * C;
    __shared__ float accLds[H][C];
    int n = blockIdx.x;
    int t = threadIdx.x;
    int h = t >> 6, lane = t & 63;
    int o0 = offsets[n];
    int deg = offsets[n + 1] - o0;

    float a[VEC], r[VEC], acc[VEC];
    {
        const float* pa = att + h * C + lane * VEC;
        const float* pr = xr + (size_t)n * HC + h * C + lane * VEC;
        if constexpr (VEC == 4) {
            float4 va = *(const float4*)pa; a[0]=va.x; a[1]=va.y; a[2]=va.z; a[3]=va.w;
            float4 vr = *(const float4*)pr; r[0]=vr.x; r[1]=vr.y; r[2]=vr.z; r[3]=vr.w;
        } else {
            float2 va = *(const float2*)pa; a[0]=va.x; a[1]=va.y;
            float2 vr = *(const float2*)pr; r[0]=vr.x; r[1]=vr.y;
        }
    }
#pragma unroll
    for (int v = 0; v < VEC; ++v) acc[v] = 0.f;
    float m = -1e30f, s = 0.f;

    for (int j = 0; j < deg; ++j) {
        int sj = esrc[o0 + j];
        const float* px = xl + (size_t)sj * HC + h * C + lane * VEC;
        float xv[VEC];
        if constexpr (VEC == 4) {
            float4 v4 = *(const float4*)px; xv[0]=v4.x; xv[1]=v4.y; xv[2]=v4.z; xv[3]=v4.w;
        } else {
            float2 v2 = *(const float2*)px; xv[0]=v2.x; xv[1]=v2.y;
        }
        float p = 0.f;
#pragma unroll
        for (int v = 0; v < VEC; ++v) p += a[v] * lrelu(xv[v] + r[v]);
#pragma unroll
        for (int st = 32; st > 0; st >>= 1) p += __shfl_xor(p, st);
        // branchless online-softmax update
        float nm = fmaxf(m, p);
        float scale = __expf(m - nm);
        float w = __expf(p - nm);
        s = s * scale + w;
#pragma unroll
        for (int v = 0; v < VEC; ++v) acc[v] = acc[v] * scale + w * xv[v];
        m = nm;
    }

    float inv = 1.0f / s;
#pragma unroll
    for (int v = 0; v < VEC; ++v) accLds[h][lane * VEC + v] = acc[v] * inv;
    __syncthreads();

    if (t < C) {
        float v = 0.f;
#pragma unroll
        for (int hh = 0; hh < H; ++hh) v += accLds[hh][t];
        v = v * 0.25f + bias[t];
        if (ACT == 0) v = lrelu(v);
        else          v = tanhf(v);
        out[(size_t)n * C + t] = v;
    }
}

// ---------------- launch ----------------

extern "C" void kernel_launch(void* const* d_in, const int* in_sizes, int n_in,
                              void* d_out, int out_size, void* d_ws, size_t ws_size,
                              hipStream_t stream) {
    const float* x    = (const float*)d_in[0];
    const int*   ei   = (const int*)d_in[1];     // int32 per harness contract
    const float* Wl1  = (const float*)d_in[2];
    const float* Wr1  = (const float*)d_in[3];
    const float* att1 = (const float*)d_in[4];
    const float* b1   = (const float*)d_in[5];
    const float* Wl2  = (const float*)d_in[6];
    const float* Wr2  = (const float*)d_in[7];
    const float* att2 = (const float*)d_in[8];
    const float* b2   = (const float*)d_in[9];
    float* out = (float*)d_out;

    const int IN = 512, HID = 256, OUT = 128, H = 4;
    int N  = in_sizes[0] / IN;
    int E  = in_sizes[1] / 2;
    int ET = E + N;

    // workspace carve (~93 MB)
    char* w = (char*)d_ws;
    auto carve = [&](size_t bytes) {
        char* p = w;
        w += (bytes + 255) & ~(size_t)255;
        return (void*)p;
    };
    float* xl1 = (float*)carve((size_t)N * H * HID * 4);   // reused: xl2 + xr2
    float* xr1 = (float*)carve((size_t)N * H * HID * 4);
    float* h1  = (float*)carve((size_t)N * HID * 4);       // separate: fused reads xr1 while writing h1
    int*   src     = (int*)carve((size_t)ET * 4);
    int*   dst     = (int*)carve((size_t)ET * 4);
    int*   counts  = (int*)carve((size_t)N * 4);
    int*   offsets = (int*)carve((size_t)(N + 1) * 4);
    int*   cursor  = (int*)carve((size_t)N * 4);
    int*   esrc    = (int*)carve((size_t)ET * 4);          // dst-sorted source ids
    float* xl2 = xl1;
    float* xr2 = xl1 + (size_t)N * H * OUT;

    // ---- CSR build ----
    zero_int<<<(N + 255) / 256, 256, 0, stream>>>(counts, N);
    build_edges<<<(ET + 255) / 256, 256, 0, stream>>>(ei, E, N, src, dst, counts);
    scan_offsets<<<1, 1024, 0, stream>>>(counts, offsets, N);
    zero_int<<<(N + 255) / 256, 256, 0, stream>>>(cursor, N);
    fill_eids<<<(ET + 255) / 256, 256, 0, stream>>>(src, dst, offsets, cursor, esrc, ET);

    // ---- layer 1: GATv2(512 -> 256, H=4, mean) + leaky_relu ----
    {
        dim3 g((H * HID) / 64, (N + 63) / 64);
        gemm_f32<<<g, 256, 0, stream>>>(x, Wl1, xl1, N, H * HID, IN);
        gemm_f32<<<g, 256, 0, stream>>>(x, Wr1, xr1, N, H * HID, IN);
    }
    fused_agg<256, 0><<<N, 256, 0, stream>>>(xl1, xr1, att1, offsets, esrc, b1, h1, N);

    // ---- layer 2: GATv2(256 -> 128, H=4, mean) + tanh ----
    {
        dim3 g((H * OUT) / 64, (N + 63) / 64);
        gemm_f32<<<g, 256, 0, stream>>>(h1, Wl2, xl2, N, H * OUT, HID);
        gemm_f32<<<g, 256, 0, stream>>>(h1, Wr2, xr2, N, H * OUT, HID);
    }
    fused_agg<128, 1><<<N, 256, 0, stream>>>(xl2, xr2, att2, offsets, esrc, b2, out, N);
}

// Round 4
// 336.594 us; speedup vs baseline: 2.6298x; 1.7666x over previous
//
#include <hip/hip_runtime.h>
#include <hip/hip_bf16.h>
#include <math.h>

#define DEVINL __device__ __forceinline__

typedef __attribute__((ext_vector_type(8))) short bf16x8;
typedef __attribute__((ext_vector_type(4))) float f32x4;

DEVINL float lrelu(float x) { return x > 0.f ? x : 0.2f * x; }

DEVINL unsigned short f2bf_rne(float f) {
    unsigned u = __float_as_uint(f);
    unsigned r = u + 0x7fff + ((u >> 16) & 1);
    return (unsigned short)(r >> 16);
}
DEVINL float bf2f(unsigned short h) { return __uint_as_float(((unsigned)h) << 16); }

DEVINL void gload_lds16(const void* g, void* l) {
    __builtin_amdgcn_global_load_lds(
        (const __attribute__((address_space(1))) void*)g,
        (__attribute__((address_space(3))) void*)l, 16, 0, 0);
}

// ---------------- utility kernels ----------------

__global__ void zero_int(int* __restrict__ p, int n) {
    int i = blockIdx.x * 256 + threadIdx.x;
    if (i < n) p[i] = 0;
}

__global__ void build_edges(const int* __restrict__ ei, int E, int N,
                            int* __restrict__ src, int* __restrict__ dst,
                            int* __restrict__ counts) {
    int e = blockIdx.x * 256 + threadIdx.x;
    int ET = E + N;
    if (e >= ET) return;
    int s, d;
    if (e < E) { s = ei[e]; d = ei[E + e]; }
    else       { s = d = e - E; }
    s = min(max(s, 0), N - 1);
    d = min(max(d, 0), N - 1);
    src[e] = s;
    dst[e] = d;
    atomicAdd(&counts[d], 1);
}

__global__ void scan_offsets(const int* __restrict__ counts, int* __restrict__ offsets, int N) {
    const int T = 1024;
    __shared__ int sums[T];
    int t = threadIdx.x;
    int chunk = (N + T - 1) / T;
    int base = t * chunk;
    int local[16];
    int s = 0;
    for (int i = 0; i < chunk; ++i) {
        int v = (base + i < N) ? counts[base + i] : 0;
        local[i] = s;
        s += v;
    }
    sums[t] = s;
    __syncthreads();
    for (int d = 1; d < T; d <<= 1) {
        int v = (t >= d) ? sums[t - d] : 0;
        __syncthreads();
        sums[t] += v;
        __syncthreads();
    }
    int excl = (t == 0) ? 0 : sums[t - 1];
    for (int i = 0; i < chunk; ++i)
        if (base + i < N) offsets[base + i] = excl + local[i];
    if (t == T - 1) offsets[N] = excl + s;
}

__global__ void fill_eids(const int* __restrict__ src, const int* __restrict__ dst,
                          const int* __restrict__ offsets,
                          int* __restrict__ cursor, int* __restrict__ esrc, int ET) {
    int e = blockIdx.x * 256 + threadIdx.x;
    if (e >= ET) return;
    int d = dst[e];
    int pos = offsets[d] + atomicAdd(&cursor[d], 1);
    esrc[pos] = src[e];
}

// ---------------- f32 -> (hi, lo) bf16 split, zero-padded rows >= M ----------------
// idx covers M2*K/4 float4 groups; K power of 2 (log2K given).
__global__ void conv_split(const float* __restrict__ x,
                           unsigned short* __restrict__ hi, unsigned short* __restrict__ lo,
                           int M, int M2, int log2K, int total4) {
    int i = blockIdx.x * 256 + threadIdx.x;
    if (i >= total4) return;
    int e = i * 4;
    int row = e >> log2K;
    ushort4 vh, vl;
    if (row < M) {
        float4 v = *(const float4*)&x[e];
        float f[4] = {v.x, v.y, v.z, v.w};
        unsigned short h[4], l[4];
#pragma unroll
        for (int j = 0; j < 4; ++j) {
            h[j] = f2bf_rne(f[j]);
            l[j] = f2bf_rne(f[j] - bf2f(h[j]));
        }
        vh = make_ushort4(h[0], h[1], h[2], h[3]);
        vl = make_ushort4(l[0], l[1], l[2], l[3]);
    } else {
        vh = make_ushort4(0, 0, 0, 0);
        vl = make_ushort4(0, 0, 0, 0);
    }
    *(ushort4*)&hi[e] = vh;
    *(ushort4*)&lo[e] = vl;
}

// ---------------- W[K][Nout] f32 -> BT[Nout][K] (hi, lo) bf16 ----------------
__global__ void tsplit(const float* __restrict__ W,
                       unsigned short* __restrict__ BTh, unsigned short* __restrict__ BTl,
                       int K, int Nout) {
    __shared__ float tile[32][33];
    int n0 = blockIdx.x * 32, k0 = blockIdx.y * 32;
    int tx = threadIdx.x, ty = threadIdx.y;
#pragma unroll
    for (int i = 0; i < 4; ++i)
        tile[ty + 8 * i][tx] = W[(size_t)(k0 + ty + 8 * i) * Nout + n0 + tx];
    __syncthreads();
#pragma unroll
    for (int i = 0; i < 4; ++i) {
        int r = ty + 8 * i;                 // n offset
        float v = tile[tx][r];              // W[k0+tx][n0+r]
        unsigned short h = f2bf_rne(v);
        unsigned short l = f2bf_rne(v - bf2f(h));
        BTh[(size_t)(n0 + r) * K + k0 + tx] = h;
        BTl[(size_t)(n0 + r) * K + k0 + tx] = l;
    }
}

// ---------------- split-bf16 MFMA GEMM: C[M][Nout] = A[M2][K] @ BT[Nout][K]^T ----------------
// 128x128 tile, BK=64, 4 waves (2x2), 16x16x32 bf16 MFMA, 3-term hi/lo split.
// LDS tiles staged via global_load_lds with T2 XOR-swizzle (pre-swizzled source).
__global__ __launch_bounds__(256) void gemm_split_mfma(
    const unsigned short* __restrict__ Ah, const unsigned short* __restrict__ Al,
    const unsigned short* __restrict__ Bh, const unsigned short* __restrict__ Bl,
    float* __restrict__ C, int M, int Nout, int K) {
    __shared__ __align__(16) char lds[65536];  // Ah|Al|Bh|Bl tiles, 16KB each
    const int t = threadIdx.x;
    const int L = t & 63, w = t >> 6;
    const int wm = w & 1, wn = w >> 1;
    const int bm = blockIdx.y * 128, bn = blockIdx.x * 128;
    const size_t strideA = (size_t)K * 2;   // bytes per row

    const f32x4 vzero = {0.f, 0.f, 0.f, 0.f};
    f32x4 acc[4][4];
#pragma unroll
    for (int i = 0; i < 4; ++i)
#pragma unroll
        for (int j = 0; j < 4; ++j) acc[i][j] = vzero;

    for (int k0 = 0; k0 < K; k0 += 64) {
        // ---- stage 4 x 16KB tiles; source pre-swizzled so swizzled-read matches ----
#pragma unroll
        for (int i = 0; i < 4; ++i) {
            int slot = i * 256 + t;
            int offs = slot * 16;                       // lds byte offset (linear dest)
            int r = offs >> 7;                          // tile row 0..127
            int cb = (offs & 127) ^ ((r & 7) << 4);     // unswizzled col byte
            size_t gofs = (size_t)r * strideA + (size_t)k0 * 2 + cb;
            gload_lds16((const char*)Ah + (size_t)(bm)*strideA + gofs, lds + offs);
            gload_lds16((const char*)Al + (size_t)(bm)*strideA + gofs, lds + 16384 + offs);
            gload_lds16((const char*)Bh + (size_t)(bn)*strideA + gofs, lds + 32768 + offs);
            gload_lds16((const char*)Bl + (size_t)(bn)*strideA + gofs, lds + 49152 + offs);
        }
        __syncthreads();
        // ---- compute: 2 k-frags x 16 frag-pairs x 3 MFMA ----
#pragma unroll
        for (int kf = 0; kf < 2; ++kf) {
            const int kb = kf * 64 + ((L >> 4) * 16);   // byte offset of this lane's k-group
            bf16x8 ah[4], al[4], bh[4], bl[4];
#pragma unroll
            for (int mi = 0; mi < 4; ++mi) {
                int r = wm * 64 + mi * 16 + (L & 15);
                int off = r * 128 + (kb ^ ((r & 7) << 4));
                ah[mi] = *(const bf16x8*)(lds + off);
                al[mi] = *(const bf16x8*)(lds + 16384 + off);
            }
#pragma unroll
            for (int ni = 0; ni < 4; ++ni) {
                int r = wn * 64 + ni * 16 + (L & 15);
                int off = r * 128 + (kb ^ ((r & 7) << 4));
                bh[ni] = *(const bf16x8*)(lds + 32768 + off);
                bl[ni] = *(const bf16x8*)(lds + 49152 + off);
            }
#pragma unroll
            for (int mi = 0; mi < 4; ++mi)
#pragma unroll
                for (int ni = 0; ni < 4; ++ni) {
                    acc[mi][ni] = __builtin_amdgcn_mfma_f32_16x16x32_bf16(ah[mi], bh[ni], acc[mi][ni], 0, 0, 0);
                    acc[mi][ni] = __builtin_amdgcn_mfma_f32_16x16x32_bf16(al[mi], bh[ni], acc[mi][ni], 0, 0, 0);
                    acc[mi][ni] = __builtin_amdgcn_mfma_f32_16x16x32_bf16(ah[mi], bl[ni], acc[mi][ni], 0, 0, 0);
                }
        }
        __syncthreads();
    }
    // ---- epilogue: C/D layout col=lane&15, row=(lane>>4)*4+reg ----
    const int colBase = bn + wn * 64 + (L & 15);
#pragma unroll
    for (int mi = 0; mi < 4; ++mi) {
        int row0 = bm + wm * 64 + mi * 16 + (L >> 4) * 4;
#pragma unroll
        for (int j = 0; j < 4; ++j) {
            int row = row0 + j;
            if (row < M) {
#pragma unroll
                for (int ni = 0; ni < 4; ++ni)
                    C[(size_t)row * Nout + colBase + ni * 16] = acc[mi][ni][j];
            }
        }
    }
}

// ---------------- fused edge-logits + online segment softmax + aggregate ----------------
// SPLIT=true: write hi/lo bf16 (padded rows [N,M2) zeroed); else write f32 out.
template <int C, int ACT, bool SPLIT>
__global__ __launch_bounds__(256) void fused_agg(const float* __restrict__ xl,
                                                 const float* __restrict__ xr,
                                                 const float* __restrict__ att,
                                                 const int* __restrict__ offsets,
                                                 const int* __restrict__ esrc,
                                                 const float* __restrict__ bias,
                                                 float* __restrict__ outF,
                                                 unsigned short* __restrict__ outH,
                                                 unsigned short* __restrict__ outL,
                                                 int N) {
    const int H = 4;
    constexpr int VEC = C / 64;
    constexpr int HC = H * C;
    __shared__ float accLds[H][C];
    int n = blockIdx.x;
    int t = threadIdx.x;
    if (SPLIT && n >= N) {       // zero-pad rows for downstream MFMA GEMM
        if (t < C) {
            outH[(size_t)n * C + t] = 0;
            outL[(size_t)n * C + t] = 0;
        }
        return;
    }
    int h = t >> 6, lane = t & 63;
    int o0 = offsets[n];
    int deg = offsets[n + 1] - o0;

    float a[VEC], r[VEC], acc[VEC];
    {
        const float* pa = att + h * C + lane * VEC;
        const float* pr = xr + (size_t)n * HC + h * C + lane * VEC;
        if constexpr (VEC == 4) {
            float4 va = *(const float4*)pa; a[0]=va.x; a[1]=va.y; a[2]=va.z; a[3]=va.w;
            float4 vr = *(const float4*)pr; r[0]=vr.x; r[1]=vr.y; r[2]=vr.z; r[3]=vr.w;
        } else {
            float2 va = *(const float2*)pa; a[0]=va.x; a[1]=va.y;
            float2 vr = *(const float2*)pr; r[0]=vr.x; r[1]=vr.y;
        }
    }
#pragma unroll
    for (int v = 0; v < VEC; ++v) acc[v] = 0.f;
    float m = -1e30f, s = 0.f;

    for (int j = 0; j < deg; ++j) {
        int sj = esrc[o0 + j];
        const float* px = xl + (size_t)sj * HC + h * C + lane * VEC;
        float xv[VEC];
        if constexpr (VEC == 4) {
            float4 v4 = *(const float4*)px; xv[0]=v4.x; xv[1]=v4.y; xv[2]=v4.z; xv[3]=v4.w;
        } else {
            float2 v2 = *(const float2*)px; xv[0]=v2.x; xv[1]=v2.y;
        }
        float p = 0.f;
#pragma unroll
        for (int v = 0; v < VEC; ++v) p += a[v] * lrelu(xv[v] + r[v]);
#pragma unroll
        for (int st = 32; st > 0; st >>= 1) p += __shfl_xor(p, st);
        float nm = fmaxf(m, p);
        float scale = __expf(m - nm);
        float wgt = __expf(p - nm);
        s = s * scale + wgt;
#pragma unroll
        for (int v = 0; v < VEC; ++v) acc[v] = acc[v] * scale + wgt * xv[v];
        m = nm;
    }

    float inv = 1.0f / s;
#pragma unroll
    for (int v = 0; v < VEC; ++v) accLds[h][lane * VEC + v] = acc[v] * inv;
    __syncthreads();

    if (t < C) {
        float v = 0.f;
#pragma unroll
        for (int hh = 0; hh < H; ++hh) v += accLds[hh][t];
        v = v * 0.25f + bias[t];
        if (ACT == 0) v = lrelu(v);
        else          v = tanhf(v);
        if (SPLIT) {
            unsigned short hh16 = f2bf_rne(v);
            outH[(size_t)n * C + t] = hh16;
            outL[(size_t)n * C + t] = f2bf_rne(v - bf2f(hh16));
        } else {
            outF[(size_t)n * C + t] = v;
        }
    }
}

// ---------------- launch ----------------

extern "C" void kernel_launch(void* const* d_in, const int* in_sizes, int n_in,
                              void* d_out, int out_size, void* d_ws, size_t ws_size,
                              hipStream_t stream) {
    const float* x    = (const float*)d_in[0];
    const int*   ei   = (const int*)d_in[1];
    const float* Wl1  = (const float*)d_in[2];
    const float* Wr1  = (const float*)d_in[3];
    const float* att1 = (const float*)d_in[4];
    const float* b1   = (const float*)d_in[5];
    const float* Wl2  = (const float*)d_in[6];
    const float* Wr2  = (const float*)d_in[7];
    const float* att2 = (const float*)d_in[8];
    const float* b2   = (const float*)d_in[9];
    float* out = (float*)d_out;

    const int IN = 512, HID = 256, OUT = 128, H = 4;
    int N  = in_sizes[0] / IN;
    int E  = in_sizes[1] / 2;
    int ET = E + N;
    int M2 = ((N + 127) / 128) * 128;   // 10112

    char* w = (char*)d_ws;
    auto carve = [&](size_t bytes) {
        char* p = w;
        w += (bytes + 255) & ~(size_t)255;
        return (void*)p;
    };
    // A splits (x): [M2][512] hi/lo bf16; reused later as h1 hi/lo ([M2][256])
    unsigned short* x_hi = (unsigned short*)carve((size_t)M2 * IN * 2);
    unsigned short* x_lo = (unsigned short*)carve((size_t)M2 * IN * 2);
    // BT splits layer 1 (reused for layer 2)
    unsigned short* BT1l_h = (unsigned short*)carve((size_t)(H * HID) * IN * 2);
    unsigned short* BT1l_l = (unsigned short*)carve((size_t)(H * HID) * IN * 2);
    unsigned short* BT1r_h = (unsigned short*)carve((size_t)(H * HID) * IN * 2);
    unsigned short* BT1r_l = (unsigned short*)carve((size_t)(H * HID) * IN * 2);
    float* xl1 = (float*)carve((size_t)N * H * HID * 4);
    float* xr1 = (float*)carve((size_t)N * H * HID * 4);
    int* src     = (int*)carve((size_t)ET * 4);
    int* dst     = (int*)carve((size_t)ET * 4);
    int* counts  = (int*)carve((size_t)N * 4);
    int* offsets = (int*)carve((size_t)(N + 1) * 4);
    int* cursor  = (int*)carve((size_t)N * 4);
    int* esrc    = (int*)carve((size_t)ET * 4);
    // aliases
    unsigned short* h1_h = x_hi;            // [M2][256] (x dead after L1 GEMMs)
    unsigned short* h1_l = x_lo;
    unsigned short* BT2l_h = BT1l_h;        // [512][256] (BT1 dead after L1 GEMMs)
    unsigned short* BT2l_l = BT1l_l;
    unsigned short* BT2r_h = BT1r_h;
    unsigned short* BT2r_l = BT1r_l;
    float* xl2 = xl1;                       // [N][512]
    float* xr2 = xr1;

    // ---- CSR build ----
    zero_int<<<(N + 255) / 256, 256, 0, stream>>>(counts, N);
    build_edges<<<(ET + 255) / 256, 256, 0, stream>>>(ei, E, N, src, dst, counts);
    scan_offsets<<<1, 1024, 0, stream>>>(counts, offsets, N);
    zero_int<<<(N + 255) / 256, 256, 0, stream>>>(cursor, N);
    fill_eids<<<(ET + 255) / 256, 256, 0, stream>>>(src, dst, offsets, cursor, esrc, ET);

    // ---- prep layer 1 ----
    {
        int total4 = M2 * IN / 4;
        conv_split<<<(total4 + 255) / 256, 256, 0, stream>>>(x, x_hi, x_lo, N, M2, 9, total4);
        tsplit<<<dim3((H * HID) / 32, IN / 32), dim3(32, 8), 0, stream>>>(Wl1, BT1l_h, BT1l_l, IN, H * HID);
        tsplit<<<dim3((H * HID) / 32, IN / 32), dim3(32, 8), 0, stream>>>(Wr1, BT1r_h, BT1r_l, IN, H * HID);
    }
    // ---- layer 1 GEMMs: [M2][512] @ [512][1024] ----
    {
        dim3 g((H * HID) / 128, M2 / 128);
        gemm_split_mfma<<<g, 256, 0, stream>>>(x_hi, x_lo, BT1l_h, BT1l_l, xl1, N, H * HID, IN);
        gemm_split_mfma<<<g, 256, 0, stream>>>(x_hi, x_lo, BT1r_h, BT1r_l, xr1, N, H * HID, IN);
    }
    // ---- layer 1 aggregate -> h1 split (padded) ----
    fused_agg<256, 0, true><<<M2, 256, 0, stream>>>(xl1, xr1, att1, offsets, esrc, b1,
                                                    nullptr, h1_h, h1_l, N);
    // ---- prep layer 2 ----
    tsplit<<<dim3((H * OUT) / 32, HID / 32), dim3(32, 8), 0, stream>>>(Wl2, BT2l_h, BT2l_l, HID, H * OUT);
    tsplit<<<dim3((H * OUT) / 32, HID / 32), dim3(32, 8), 0, stream>>>(Wr2, BT2r_h, BT2r_l, HID, H * OUT);
    // ---- layer 2 GEMMs: [M2][256] @ [256][512] ----
    {
        dim3 g((H * OUT) / 128, M2 / 128);
        gemm_split_mfma<<<g, 256, 0, stream>>>(h1_h, h1_l, BT2l_h, BT2l_l, xl2, N, H * OUT, HID);
        gemm_split_mfma<<<g, 256, 0, stream>>>(h1_h, h1_l, BT2r_h, BT2r_l, xr2, N, H * OUT, HID);
    }
    // ---- layer 2 aggregate -> out ----
    fused_agg<128, 1, false><<<N, 256, 0, stream>>>(xl2, xr2, att2, offsets, esrc, b2,
                                                    out, nullptr, nullptr, N);
}

// Round 5
// 268.092 us; speedup vs baseline: 3.3017x; 1.2555x over previous
//
#include <hip/hip_runtime.h>
#include <hip/hip_bf16.h>
#include <math.h>

#define DEVINL __device__ __forceinline__

typedef __attribute__((ext_vector_type(8))) short bf16x8;
typedef __attribute__((ext_vector_type(4))) float f32x4;

DEVINL float lrelu(float x) { return x > 0.f ? x : 0.2f * x; }

DEVINL unsigned short f2bf_rne(float f) {
    unsigned u = __float_as_uint(f);
    unsigned r = u + 0x7fff + ((u >> 16) & 1);
    return (unsigned short)(r >> 16);
}
DEVINL float bf2f(unsigned short h) { return __uint_as_float(((unsigned)h) << 16); }

DEVINL void gload_lds16(const void* g, void* l) {
    __builtin_amdgcn_global_load_lds(
        (const __attribute__((address_space(1))) void*)g,
        (__attribute__((address_space(3))) void*)l, 16, 0, 0);
}

// ---------------- utility kernels ----------------

__global__ void zero_int(int* __restrict__ p, int n) {
    int i = blockIdx.x * 256 + threadIdx.x;
    if (i < n) p[i] = 0;
}

__global__ void build_edges(const int* __restrict__ ei, int E, int N,
                            int* __restrict__ src, int* __restrict__ dst,
                            int* __restrict__ counts) {
    int e = blockIdx.x * 256 + threadIdx.x;
    int ET = E + N;
    if (e >= ET) return;
    int s, d;
    if (e < E) { s = ei[e]; d = ei[E + e]; }
    else       { s = d = e - E; }
    s = min(max(s, 0), N - 1);
    d = min(max(d, 0), N - 1);
    src[e] = s;
    dst[e] = d;
    atomicAdd(&counts[d], 1);
}

__global__ void scan_offsets(const int* __restrict__ counts, int* __restrict__ offsets, int N) {
    const int T = 1024;
    __shared__ int sums[T];
    int t = threadIdx.x;
    int chunk = (N + T - 1) / T;
    int base = t * chunk;
    int local[16];
    int s = 0;
    for (int i = 0; i < chunk; ++i) {
        int v = (base + i < N) ? counts[base + i] : 0;
        local[i] = s;
        s += v;
    }
    sums[t] = s;
    __syncthreads();
    for (int d = 1; d < T; d <<= 1) {
        int v = (t >= d) ? sums[t - d] : 0;
        __syncthreads();
        sums[t] += v;
        __syncthreads();
    }
    int excl = (t == 0) ? 0 : sums[t - 1];
    for (int i = 0; i < chunk; ++i)
        if (base + i < N) offsets[base + i] = excl + local[i];
    if (t == T - 1) offsets[N] = excl + s;
}

__global__ void fill_eids(const int* __restrict__ src, const int* __restrict__ dst,
                          const int* __restrict__ offsets,
                          int* __restrict__ cursor, int* __restrict__ esrc, int ET) {
    int e = blockIdx.x * 256 + threadIdx.x;
    if (e >= ET) return;
    int d = dst[e];
    int pos = offsets[d] + atomicAdd(&cursor[d], 1);
    esrc[pos] = src[e];
}

// ---------------- f32 -> hi bf16 (RNE), zero-padded rows >= M ----------------
__global__ void conv_hi(const float* __restrict__ x, unsigned short* __restrict__ hi,
                        int M, int log2K, int total4) {
    int i = blockIdx.x * 256 + threadIdx.x;
    if (i >= total4) return;
    int e = i * 4;
    int row = e >> log2K;
    ushort4 vh = make_ushort4(0, 0, 0, 0);
    if (row < M) {
        float4 v = *(const float4*)&x[e];
        vh = make_ushort4(f2bf_rne(v.x), f2bf_rne(v.y), f2bf_rne(v.z), f2bf_rne(v.w));
    }
    *(ushort4*)&hi[e] = vh;
}

// ---------------- W[K][Nout] f32 -> BT[Nout][K] hi bf16 ----------------
__global__ void thi(const float* __restrict__ W, unsigned short* __restrict__ BTh,
                    int K, int Nout) {
    __shared__ float tile[32][33];
    int n0 = blockIdx.x * 32, k0 = blockIdx.y * 32;
    int tx = threadIdx.x, ty = threadIdx.y;
#pragma unroll
    for (int i = 0; i < 4; ++i)
        tile[ty + 8 * i][tx] = W[(size_t)(k0 + ty + 8 * i) * Nout + n0 + tx];
    __syncthreads();
#pragma unroll
    for (int i = 0; i < 4; ++i) {
        int r = ty + 8 * i;
        BTh[(size_t)(n0 + r) * K + k0 + tx] = f2bf_rne(tile[tx][r]);
    }
}

// ---------------- bf16 MFMA GEMM: C[M][Nout] = A[M2][K] @ BT[Nout][K]^T ----------------
// 128x128 tile, BK=64, 4 waves (2x2), 16x16x32 bf16 MFMA.
// TERMS=1: C = Ah.Bh (pure bf16). TERMS=2: C = Ah.Bh + Al.Bh (A split, B bf16).
// OUTBF16: write bf16 (RNE) instead of f32.
template <int TERMS, bool OUTBF16>
__global__ __launch_bounds__(256) void gemm_mfma(
    const unsigned short* __restrict__ Ah, const unsigned short* __restrict__ Al,
    const unsigned short* __restrict__ Bh,
    float* __restrict__ Cf, unsigned short* __restrict__ Cb,
    int M, int Nout, int K) {
    constexpr int BOFF = (TERMS == 2) ? 32768 : 16384;   // LDS offset of B tile
    __shared__ __align__(16) char lds[BOFF + 16384];
    const int t = threadIdx.x;
    const int L = t & 63, w = t >> 6;
    const int wm = w & 1, wn = w >> 1;
    const int bm = blockIdx.y * 128, bn = blockIdx.x * 128;
    const size_t strideA = (size_t)K * 2;   // bytes per row

    const f32x4 vzero = {0.f, 0.f, 0.f, 0.f};
    f32x4 acc[4][4];
#pragma unroll
    for (int i = 0; i < 4; ++i)
#pragma unroll
        for (int j = 0; j < 4; ++j) acc[i][j] = vzero;

    for (int k0 = 0; k0 < K; k0 += 64) {
        // ---- stage tiles; source pre-swizzled so swizzled-read matches (rule 21) ----
#pragma unroll
        for (int i = 0; i < 4; ++i) {
            int slot = i * 256 + t;
            int offs = slot * 16;                       // lds byte offset (linear dest)
            int r = offs >> 7;                          // tile row 0..127
            int cb = (offs & 127) ^ ((r & 7) << 4);     // unswizzled col byte
            size_t gofs = (size_t)r * strideA + (size_t)k0 * 2 + cb;
            gload_lds16((const char*)Ah + (size_t)bm * strideA + gofs, lds + offs);
            if constexpr (TERMS == 2)
                gload_lds16((const char*)Al + (size_t)bm * strideA + gofs, lds + 16384 + offs);
            gload_lds16((const char*)Bh + (size_t)bn * strideA + gofs, lds + BOFF + offs);
        }
        __syncthreads();
        // ---- compute ----
#pragma unroll
        for (int kf = 0; kf < 2; ++kf) {
            const int kb = kf * 64 + ((L >> 4) * 16);
            bf16x8 ah[4], al[4], bh[4];
#pragma unroll
            for (int mi = 0; mi < 4; ++mi) {
                int r = wm * 64 + mi * 16 + (L & 15);
                int off = r * 128 + (kb ^ ((r & 7) << 4));
                ah[mi] = *(const bf16x8*)(lds + off);
                if constexpr (TERMS == 2) al[mi] = *(const bf16x8*)(lds + 16384 + off);
            }
#pragma unroll
            for (int ni = 0; ni < 4; ++ni) {
                int r = wn * 64 + ni * 16 + (L & 15);
                int off = r * 128 + (kb ^ ((r & 7) << 4));
                bh[ni] = *(const bf16x8*)(lds + BOFF + off);
            }
#pragma unroll
            for (int mi = 0; mi < 4; ++mi)
#pragma unroll
                for (int ni = 0; ni < 4; ++ni) {
                    acc[mi][ni] = __builtin_amdgcn_mfma_f32_16x16x32_bf16(ah[mi], bh[ni], acc[mi][ni], 0, 0, 0);
                    if constexpr (TERMS == 2)
                        acc[mi][ni] = __builtin_amdgcn_mfma_f32_16x16x32_bf16(al[mi], bh[ni], acc[mi][ni], 0, 0, 0);
                }
        }
        __syncthreads();
    }
    // ---- epilogue: C/D layout col=lane&15, row=(lane>>4)*4+reg ----
    const int colBase = bn + wn * 64 + (L & 15);
#pragma unroll
    for (int mi = 0; mi < 4; ++mi) {
        int row0 = bm + wm * 64 + mi * 16 + (L >> 4) * 4;
#pragma unroll
        for (int j = 0; j < 4; ++j) {
            int row = row0 + j;
            if (row < M) {
#pragma unroll
                for (int ni = 0; ni < 4; ++ni) {
                    if constexpr (OUTBF16)
                        Cb[(size_t)row * Nout + colBase + ni * 16] = f2bf_rne(acc[mi][ni][j]);
                    else
                        Cf[(size_t)row * Nout + colBase + ni * 16] = acc[mi][ni][j];
                }
            }
        }
    }
}

// ---------------- fused edge-logits + online segment softmax + aggregate ----------------
// INBF16: xl/xr are bf16 (ushort); else f32.
// SPLIT=true: write hi/lo bf16 (padded rows [N,M2) zeroed); else write f32 out.
template <int C, int ACT, bool SPLIT, bool INBF16>
__global__ __launch_bounds__(256) void fused_agg(const void* __restrict__ xlv,
                                                 const void* __restrict__ xrv,
                                                 const float* __restrict__ att,
                                                 const int* __restrict__ offsets,
                                                 const int* __restrict__ esrc,
                                                 const float* __restrict__ bias,
                                                 float* __restrict__ outF,
                                                 unsigned short* __restrict__ outH,
                                                 unsigned short* __restrict__ outL,
                                                 int N) {
    const int H = 4;
    constexpr int VEC = C / 64;
    constexpr int HC = H * C;
    __shared__ float accLds[H][C];
    int n = blockIdx.x;
    int t = threadIdx.x;
    if (SPLIT && n >= N) {
        if (t < C) {
            outH[(size_t)n * C + t] = 0;
            outL[(size_t)n * C + t] = 0;
        }
        return;
    }
    int h = t >> 6, lane = t & 63;
    int o0 = offsets[n];
    int deg = offsets[n + 1] - o0;

    float a[VEC], r[VEC], acc[VEC];
    {
        const float* pa = att + h * C + lane * VEC;
        if constexpr (VEC == 4) {
            float4 va = *(const float4*)pa; a[0]=va.x; a[1]=va.y; a[2]=va.z; a[3]=va.w;
        } else {
            float2 va = *(const float2*)pa; a[0]=va.x; a[1]=va.y;
        }
        if constexpr (INBF16) {
            const unsigned short* pr = (const unsigned short*)xrv + (size_t)n * HC + h * C + lane * VEC;
            if constexpr (VEC == 4) {
                ushort4 u = *(const ushort4*)pr;
                r[0]=bf2f(u.x); r[1]=bf2f(u.y); r[2]=bf2f(u.z); r[3]=bf2f(u.w);
            } else {
                ushort2 u = *(const ushort2*)pr;
                r[0]=bf2f(u.x); r[1]=bf2f(u.y);
            }
        } else {
            const float* pr = (const float*)xrv + (size_t)n * HC + h * C + lane * VEC;
            if constexpr (VEC == 4) {
                float4 vr = *(const float4*)pr; r[0]=vr.x; r[1]=vr.y; r[2]=vr.z; r[3]=vr.w;
            } else {
                float2 vr = *(const float2*)pr; r[0]=vr.x; r[1]=vr.y;
            }
        }
    }
#pragma unroll
    for (int v = 0; v < VEC; ++v) acc[v] = 0.f;
    float m = -1e30f, s = 0.f;

    for (int j = 0; j < deg; ++j) {
        int sj = esrc[o0 + j];
        float xv[VEC];
        if constexpr (INBF16) {
            const unsigned short* px = (const unsigned short*)xlv + (size_t)sj * HC + h * C + lane * VEC;
            if constexpr (VEC == 4) {
                ushort4 u = *(const ushort4*)px;
                xv[0]=bf2f(u.x); xv[1]=bf2f(u.y); xv[2]=bf2f(u.z); xv[3]=bf2f(u.w);
            } else {
                ushort2 u = *(const ushort2*)px;
                xv[0]=bf2f(u.x); xv[1]=bf2f(u.y);
            }
        } else {
            const float* px = (const float*)xlv + (size_t)sj * HC + h * C + lane * VEC;
            if constexpr (VEC == 4) {
                float4 v4 = *(const float4*)px; xv[0]=v4.x; xv[1]=v4.y; xv[2]=v4.z; xv[3]=v4.w;
            } else {
                float2 v2 = *(const float2*)px; xv[0]=v2.x; xv[1]=v2.y;
            }
        }
        float p = 0.f;
#pragma unroll
        for (int v = 0; v < VEC; ++v) p += a[v] * lrelu(xv[v] + r[v]);
#pragma unroll
        for (int st = 32; st > 0; st >>= 1) p += __shfl_xor(p, st);
        float nm = fmaxf(m, p);
        float scale = __expf(m - nm);
        float wgt = __expf(p - nm);
        s = s * scale + wgt;
#pragma unroll
        for (int v = 0; v < VEC; ++v) acc[v] = acc[v] * scale + wgt * xv[v];
        m = nm;
    }

    float inv = 1.0f / s;
#pragma unroll
    for (int v = 0; v < VEC; ++v) accLds[h][lane * VEC + v] = acc[v] * inv;
    __syncthreads();

    if (t < C) {
        float v = 0.f;
#pragma unroll
        for (int hh = 0; hh < H; ++hh) v += accLds[hh][t];
        v = v * 0.25f + bias[t];
        if (ACT == 0) v = lrelu(v);
        else          v = tanhf(v);
        if (SPLIT) {
            unsigned short hh16 = f2bf_rne(v);
            outH[(size_t)n * C + t] = hh16;
            outL[(size_t)n * C + t] = f2bf_rne(v - bf2f(hh16));
        } else {
            outF[(size_t)n * C + t] = v;
        }
    }
}

// ---------------- launch ----------------

extern "C" void kernel_launch(void* const* d_in, const int* in_sizes, int n_in,
                              void* d_out, int out_size, void* d_ws, size_t ws_size,
                              hipStream_t stream) {
    const float* x    = (const float*)d_in[0];
    const int*   ei   = (const int*)d_in[1];
    const float* Wl1  = (const float*)d_in[2];
    const float* Wr1  = (const float*)d_in[3];
    const float* att1 = (const float*)d_in[4];
    const float* b1   = (const float*)d_in[5];
    const float* Wl2  = (const float*)d_in[6];
    const float* Wr2  = (const float*)d_in[7];
    const float* att2 = (const float*)d_in[8];
    const float* b2   = (const float*)d_in[9];
    float* out = (float*)d_out;

    const int IN = 512, HID = 256, OUT = 128, H = 4;
    int N  = in_sizes[0] / IN;
    int E  = in_sizes[1] / 2;
    int ET = E + N;
    int M2 = ((N + 127) / 128) * 128;   // 10112

    char* w = (char*)d_ws;
    auto carve = [&](size_t bytes) {
        char* p = w;
        w += (bytes + 255) & ~(size_t)255;
        return (void*)p;
    };
    // x_hi [M2][512] bf16; region reused as h1 hi/lo ([M2][256] each) after L1 GEMMs
    unsigned short* x_hi = (unsigned short*)carve((size_t)M2 * IN * 2);
    // xl1/xr1 bf16 [N][1024]; regions reused as xl2/xr2 f32 [N][512] after L1 aggregate
    unsigned short* xl1_bf = (unsigned short*)carve((size_t)N * H * HID * 2);
    unsigned short* xr1_bf = (unsigned short*)carve((size_t)N * H * HID * 2);
    unsigned short* BT1l_h = (unsigned short*)carve((size_t)(H * HID) * IN * 2);
    unsigned short* BT1r_h = (unsigned short*)carve((size_t)(H * HID) * IN * 2);
    int* src     = (int*)carve((size_t)ET * 4);
    int* dst     = (int*)carve((size_t)ET * 4);
    int* counts  = (int*)carve((size_t)N * 4);
    int* offsets = (int*)carve((size_t)(N + 1) * 4);
    int* cursor  = (int*)carve((size_t)N * 4);
    int* esrc    = (int*)carve((size_t)ET * 4);
    // aliases
    unsigned short* h1_h = x_hi;                              // [M2][256]
    unsigned short* h1_l = x_hi + (size_t)M2 * HID;           // [M2][256]
    unsigned short* BT2l_h = BT1l_h;                          // [512][256]
    unsigned short* BT2r_h = BT1r_h;
    float* xl2 = (float*)xl1_bf;                              // [N][512] f32
    float* xr2 = (float*)xr1_bf;

    // ---- CSR build ----
    zero_int<<<(N + 255) / 256, 256, 0, stream>>>(counts, N);
    build_edges<<<(ET + 255) / 256, 256, 0, stream>>>(ei, E, N, src, dst, counts);
    scan_offsets<<<1, 1024, 0, stream>>>(counts, offsets, N);
    zero_int<<<(N + 255) / 256, 256, 0, stream>>>(cursor, N);
    fill_eids<<<(ET + 255) / 256, 256, 0, stream>>>(src, dst, offsets, cursor, esrc, ET);

    // ---- prep layer 1 ----
    {
        int total4 = M2 * IN / 4;
        conv_hi<<<(total4 + 255) / 256, 256, 0, stream>>>(x, x_hi, N, 9, total4);
        thi<<<dim3((H * HID) / 32, IN / 32), dim3(32, 8), 0, stream>>>(Wl1, BT1l_h, IN, H * HID);
        thi<<<dim3((H * HID) / 32, IN / 32), dim3(32, 8), 0, stream>>>(Wr1, BT1r_h, IN, H * HID);
    }
    // ---- layer 1 GEMMs (pure bf16, bf16 out): [M2][512] @ [512][1024] ----
    {
        dim3 g((H * HID) / 128, M2 / 128);
        gemm_mfma<1, true><<<g, 256, 0, stream>>>(x_hi, nullptr, BT1l_h, nullptr, xl1_bf, N, H * HID, IN);
        gemm_mfma<1, true><<<g, 256, 0, stream>>>(x_hi, nullptr, BT1r_h, nullptr, xr1_bf, N, H * HID, IN);
    }
    // ---- layer 1 aggregate (bf16 in) -> h1 split (padded) ----
    fused_agg<256, 0, true, true><<<M2, 256, 0, stream>>>(xl1_bf, xr1_bf, att1, offsets, esrc, b1,
                                                          nullptr, h1_h, h1_l, N);
    // ---- prep layer 2 ----
    thi<<<dim3((H * OUT) / 32, HID / 32), dim3(32, 8), 0, stream>>>(Wl2, BT2l_h, HID, H * OUT);
    thi<<<dim3((H * OUT) / 32, HID / 32), dim3(32, 8), 0, stream>>>(Wr2, BT2r_h, HID, H * OUT);
    // ---- layer 2 GEMMs (2-term, f32 out): [M2][256] @ [256][512] ----
    {
        dim3 g((H * OUT) / 128, M2 / 128);
        gemm_mfma<2, false><<<g, 256, 0, stream>>>(h1_h, h1_l, BT2l_h, xl2, nullptr, N, H * OUT, HID);
        gemm_mfma<2, false><<<g, 256, 0, stream>>>(h1_h, h1_l, BT2r_h, xr2, nullptr, N, H * OUT, HID);
    }
    // ---- layer 2 aggregate (f32 in) -> out ----
    fused_agg<128, 1, false, false><<<N, 256, 0, stream>>>(xl2, xr2, att2, offsets, esrc, b2,
                                                           out, nullptr, nullptr, N);
}

// Round 6
// 208.390 us; speedup vs baseline: 4.2476x; 1.2865x over previous
//
#include <hip/hip_runtime.h>
#include <hip/hip_bf16.h>
#include <math.h>

#define DEVINL __device__ __forceinline__

typedef __attribute__((ext_vector_type(8))) short bf16x8;
typedef __attribute__((ext_vector_type(8))) unsigned short u16x8;
typedef __attribute__((ext_vector_type(4))) float f32x4;

DEVINL float lrelu(float x) { return x > 0.f ? x : 0.2f * x; }

DEVINL unsigned short f2bf_rne(float f) {
    unsigned u = __float_as_uint(f);
    unsigned r = u + 0x7fff + ((u >> 16) & 1);
    return (unsigned short)(r >> 16);
}
DEVINL float bf2f(unsigned short h) { return __uint_as_float(((unsigned)h) << 16); }

DEVINL void gload_lds16(const void* g, void* l) {
    __builtin_amdgcn_global_load_lds(
        (const __attribute__((address_space(1))) void*)g,
        (__attribute__((address_space(3))) void*)l, 16, 0, 0);
}

// ---------------- CSR build ----------------

__global__ void build_edges(const int* __restrict__ ei, int E, int N,
                            int* __restrict__ src, int* __restrict__ dst,
                            int* __restrict__ counts) {
    int e = blockIdx.x * 256 + threadIdx.x;
    int ET = E + N;
    if (e >= ET) return;
    int s, d;
    if (e < E) { s = ei[e]; d = ei[E + e]; }
    else       { s = d = e - E; }
    s = min(max(s, 0), N - 1);
    d = min(max(d, 0), N - 1);
    src[e] = s;
    dst[e] = d;
    atomicAdd(&counts[d], 1);
}

__global__ void scan_offsets(const int* __restrict__ counts, int* __restrict__ offsets, int N) {
    const int T = 1024;
    __shared__ int sums[T];
    int t = threadIdx.x;
    int chunk = (N + T - 1) / T;
    int base = t * chunk;
    int local[16];
    int s = 0;
    for (int i = 0; i < chunk; ++i) {
        int v = (base + i < N) ? counts[base + i] : 0;
        local[i] = s;
        s += v;
    }
    sums[t] = s;
    __syncthreads();
    for (int d = 1; d < T; d <<= 1) {
        int v = (t >= d) ? sums[t - d] : 0;
        __syncthreads();
        sums[t] += v;
        __syncthreads();
    }
    int excl = (t == 0) ? 0 : sums[t - 1];
    for (int i = 0; i < chunk; ++i)
        if (base + i < N) offsets[base + i] = excl + local[i];
    if (t == T - 1) offsets[N] = excl + s;
}

__global__ void fill_eids(const int* __restrict__ src, const int* __restrict__ dst,
                          const int* __restrict__ offsets,
                          int* __restrict__ cursor, int* __restrict__ esrc, int ET) {
    int e = blockIdx.x * 256 + threadIdx.x;
    if (e >= ET) return;
    int d = dst[e];
    int pos = offsets[d] + atomicAdd(&cursor[d], 1);
    esrc[pos] = src[e];
}

// ---------------- f32 -> hi bf16 (RNE), zero-padded rows >= M ----------------
__global__ void conv_hi(const float* __restrict__ x, unsigned short* __restrict__ hi,
                        int M, int log2K, int total4) {
    int i = blockIdx.x * 256 + threadIdx.x;
    if (i >= total4) return;
    int e = i * 4;
    int row = e >> log2K;
    ushort4 vh = make_ushort4(0, 0, 0, 0);
    if (row < M) {
        float4 v = *(const float4*)&x[e];
        vh = make_ushort4(f2bf_rne(v.x), f2bf_rne(v.y), f2bf_rne(v.z), f2bf_rne(v.w));
    }
    *(ushort4*)&hi[e] = vh;
}

// ---------------- W[K][Nout] f32 -> BT[Nout][K] hi bf16 ----------------
__global__ void thi(const float* __restrict__ W, unsigned short* __restrict__ BTh,
                    int K, int Nout) {
    __shared__ float tile[32][33];
    int n0 = blockIdx.x * 32, k0 = blockIdx.y * 32;
    int tx = threadIdx.x, ty = threadIdx.y;
#pragma unroll
    for (int i = 0; i < 4; ++i)
        tile[ty + 8 * i][tx] = W[(size_t)(k0 + ty + 8 * i) * Nout + n0 + tx];
    __syncthreads();
#pragma unroll
    for (int i = 0; i < 4; ++i) {
        int r = ty + 8 * i;
        BTh[(size_t)(n0 + r) * K + k0 + tx] = f2bf_rne(tile[tx][r]);
    }
}

// ---------------- bf16 MFMA GEMM: C[M][Nout] = A[M2][K] @ BT[Nout][K]^T ----------------
// 128x128 tile, BK=64, 4 waves (2x2), 16x16x32 bf16 MFMA, T1 bijective XCD swizzle.
// TERMS=1: C = Ah.Bh. TERMS=2: C = Ah.Bh + Al.Bh. OUTBF16: write bf16 RNE.
template <int TERMS, bool OUTBF16>
__global__ __launch_bounds__(256) void gemm_mfma(
    const unsigned short* __restrict__ Ah, const unsigned short* __restrict__ Al,
    const unsigned short* __restrict__ Bh,
    float* __restrict__ Cf, unsigned short* __restrict__ Cb,
    int M, int Nout, int K) {
    constexpr int BOFF = (TERMS == 2) ? 32768 : 16384;
    __shared__ __align__(16) char lds[BOFF + 16384];
    const int t = threadIdx.x;
    const int L = t & 63, w = t >> 6;
    const int wm = w & 1, wn = w >> 1;
    // T1 bijective XCD swizzle (m204 formula)
    const int nwg = gridDim.x * gridDim.y;
    int orig = blockIdx.y * gridDim.x + blockIdx.x;
    int q = nwg >> 3, rr = nwg & 7;
    int xcd = orig & 7, pos = orig >> 3;
    int wg = (xcd < rr ? xcd * (q + 1) : rr * (q + 1) + (xcd - rr) * q) + pos;
    const int bm = (wg / gridDim.x) * 128, bn = (wg % gridDim.x) * 128;
    const size_t strideA = (size_t)K * 2;

    const f32x4 vzero = {0.f, 0.f, 0.f, 0.f};
    f32x4 acc[4][4];
#pragma unroll
    for (int i = 0; i < 4; ++i)
#pragma unroll
        for (int j = 0; j < 4; ++j) acc[i][j] = vzero;

    for (int k0 = 0; k0 < K; k0 += 64) {
#pragma unroll
        for (int i = 0; i < 4; ++i) {
            int slot = i * 256 + t;
            int offs = slot * 16;
            int r = offs >> 7;
            int cb = (offs & 127) ^ ((r & 7) << 4);
            size_t gofs = (size_t)r * strideA + (size_t)k0 * 2 + cb;
            gload_lds16((const char*)Ah + (size_t)bm * strideA + gofs, lds + offs);
            if constexpr (TERMS == 2)
                gload_lds16((const char*)Al + (size_t)bm * strideA + gofs, lds + 16384 + offs);
            gload_lds16((const char*)Bh + (size_t)bn * strideA + gofs, lds + BOFF + offs);
        }
        __syncthreads();
#pragma unroll
        for (int kf = 0; kf < 2; ++kf) {
            const int kb = kf * 64 + ((L >> 4) * 16);
            bf16x8 ah[4], al[4], bh[4];
#pragma unroll
            for (int mi = 0; mi < 4; ++mi) {
                int r = wm * 64 + mi * 16 + (L & 15);
                int off = r * 128 + (kb ^ ((r & 7) << 4));
                ah[mi] = *(const bf16x8*)(lds + off);
                if constexpr (TERMS == 2) al[mi] = *(const bf16x8*)(lds + 16384 + off);
            }
#pragma unroll
            for (int ni = 0; ni < 4; ++ni) {
                int r = wn * 64 + ni * 16 + (L & 15);
                int off = r * 128 + (kb ^ ((r & 7) << 4));
                bh[ni] = *(const bf16x8*)(lds + BOFF + off);
            }
#pragma unroll
            for (int mi = 0; mi < 4; ++mi)
#pragma unroll
                for (int ni = 0; ni < 4; ++ni) {
                    acc[mi][ni] = __builtin_amdgcn_mfma_f32_16x16x32_bf16(ah[mi], bh[ni], acc[mi][ni], 0, 0, 0);
                    if constexpr (TERMS == 2)
                        acc[mi][ni] = __builtin_amdgcn_mfma_f32_16x16x32_bf16(al[mi], bh[ni], acc[mi][ni], 0, 0, 0);
                }
        }
        __syncthreads();
    }
    const int colBase = bn + wn * 64 + (L & 15);
#pragma unroll
    for (int mi = 0; mi < 4; ++mi) {
        int row0 = bm + wm * 64 + mi * 16 + (L >> 4) * 4;
#pragma unroll
        for (int j = 0; j < 4; ++j) {
            int row = row0 + j;
            if (row < M) {
#pragma unroll
                for (int ni = 0; ni < 4; ++ni) {
                    if constexpr (OUTBF16)
                        Cb[(size_t)row * Nout + colBase + ni * 16] = f2bf_rne(acc[mi][ni][j]);
                    else
                        Cf[(size_t)row * Nout + colBase + ni * 16] = acc[mi][ni][j];
                }
            }
        }
    }
}

// ---------------- fused edge-logits + segment softmax + aggregate ----------------
// One block per dst node; wave h handles head h. Within a wave: 4 groups of 16
// lanes process 4 edges concurrently; lane owns VEC=C/16 channels. No running
// max: logits bounded (|p| ~ <10); clamp to +-60 before exp as insurance.
// All activation inputs bf16 (RS = row stride in elements).
// SPLIT: write hi/lo bf16 h1 (padded rows [N,gridDim) zeroed); else f32 out.
template <int C, int ACT, bool SPLIT, int RS>
__global__ __launch_bounds__(256) void fused_agg(const unsigned short* __restrict__ xl,
                                                 const unsigned short* __restrict__ xr,
                                                 const float* __restrict__ att,
                                                 const int* __restrict__ offsets,
                                                 const int* __restrict__ esrc,
                                                 const float* __restrict__ bias,
                                                 float* __restrict__ outF,
                                                 unsigned short* __restrict__ outH,
                                                 unsigned short* __restrict__ outL,
                                                 int N) {
    const int H = 4;
    constexpr int VEC = C / 16;
    __shared__ float accLds[H][C];
    int n = blockIdx.x;
    int t = threadIdx.x;
    if (SPLIT && n >= N) {
        if (t < C) {
            outH[(size_t)n * C + t] = 0;
            outL[(size_t)n * C + t] = 0;
        }
        return;
    }
    int h = t >> 6, lane = t & 63;
    int g = lane >> 4, gl = lane & 15;
    int o0 = offsets[n];
    int deg = offsets[n + 1] - o0;

    float a[VEC], r[VEC], acc[VEC];
    {
        const float* pa = att + h * C + gl * VEC;
#pragma unroll
        for (int v4 = 0; v4 < VEC / 4; ++v4) {
            float4 va = *(const float4*)(pa + v4 * 4);
            a[v4 * 4 + 0] = va.x; a[v4 * 4 + 1] = va.y;
            a[v4 * 4 + 2] = va.z; a[v4 * 4 + 3] = va.w;
        }
        const unsigned short* pr = xr + (size_t)n * RS + h * C + gl * VEC;
#pragma unroll
        for (int v8 = 0; v8 < VEC / 8; ++v8) {
            u16x8 u = *(const u16x8*)(pr + v8 * 8);
#pragma unroll
            for (int j = 0; j < 8; ++j) r[v8 * 8 + j] = bf2f(u[j]);
        }
    }
#pragma unroll
    for (int v = 0; v < VEC; ++v) acc[v] = 0.f;
    float s = 0.f;

    for (int j = g; j < deg; j += 4) {
        int sj = esrc[o0 + j];
        const unsigned short* px = xl + (size_t)sj * RS + h * C + gl * VEC;
        float xv[VEC];
#pragma unroll
        for (int v8 = 0; v8 < VEC / 8; ++v8) {
            u16x8 u = *(const u16x8*)(px + v8 * 8);
#pragma unroll
            for (int q = 0; q < 8; ++q) xv[v8 * 8 + q] = bf2f(u[q]);
        }
        float p = 0.f;
#pragma unroll
        for (int v = 0; v < VEC; ++v) p += a[v] * lrelu(xv[v] + r[v]);
        // reduce within 16-lane group
        p += __shfl_xor(p, 1);
        p += __shfl_xor(p, 2);
        p += __shfl_xor(p, 4);
        p += __shfl_xor(p, 8);
        p = fminf(fmaxf(p, -60.f), 60.f);
        float wgt = __expf(p);
        s += wgt;
#pragma unroll
        for (int v = 0; v < VEC; ++v) acc[v] += wgt * xv[v];
    }
    // cross-group reduce (groups processed disjoint edge subsets)
    s += __shfl_xor(s, 16);
    s += __shfl_xor(s, 32);
#pragma unroll
    for (int v = 0; v < VEC; ++v) {
        acc[v] += __shfl_xor(acc[v], 16);
        acc[v] += __shfl_xor(acc[v], 32);
    }

    if (g == 0) {
        float inv = 1.0f / s;
#pragma unroll
        for (int v = 0; v < VEC; ++v) accLds[h][gl * VEC + v] = acc[v] * inv;
    }
    __syncthreads();

    if (t < C) {
        float v = 0.f;
#pragma unroll
        for (int hh = 0; hh < H; ++hh) v += accLds[hh][t];
        v = v * 0.25f + bias[t];
        if (ACT == 0) v = lrelu(v);
        else          v = tanhf(v);
        if (SPLIT) {
            unsigned short hh16 = f2bf_rne(v);
            outH[(size_t)n * C + t] = hh16;
            outL[(size_t)n * C + t] = f2bf_rne(v - bf2f(hh16));
        } else {
            outF[(size_t)n * C + t] = v;
        }
    }
}

// ---------------- launch ----------------

extern "C" void kernel_launch(void* const* d_in, const int* in_sizes, int n_in,
                              void* d_out, int out_size, void* d_ws, size_t ws_size,
                              hipStream_t stream) {
    const float* x    = (const float*)d_in[0];
    const int*   ei   = (const int*)d_in[1];
    const float* Wl1  = (const float*)d_in[2];
    const float* Wr1  = (const float*)d_in[3];
    const float* att1 = (const float*)d_in[4];
    const float* b1   = (const float*)d_in[5];
    const float* Wl2  = (const float*)d_in[6];
    const float* Wr2  = (const float*)d_in[7];
    const float* att2 = (const float*)d_in[8];
    const float* b2   = (const float*)d_in[9];
    float* out = (float*)d_out;

    const int IN = 512, HID = 256, OUT = 128, H = 4;
    int N  = in_sizes[0] / IN;
    int E  = in_sizes[1] / 2;
    int ET = E + N;
    int M2 = ((N + 127) / 128) * 128;   // 10112

    char* w = (char*)d_ws;
    auto carve = [&](size_t bytes) {
        char* p = w;
        w += (bytes + 255) & ~(size_t)255;
        return (void*)p;
    };
    // x_hi [M2][512] bf16; region reused as h1 hi/lo ([M2][256] each)
    unsigned short* x_hi = (unsigned short*)carve((size_t)M2 * IN * 2);
    // xlr1 [N][2048] bf16 (xl|xr combined); region reused as xlr2 [N][1024]
    unsigned short* xlr1 = (unsigned short*)carve((size_t)N * 2 * H * HID * 2);
    // BT1 combined [2048][512] bf16; region reused as BT2 [1024][256]
    unsigned short* BT1 = (unsigned short*)carve((size_t)(2 * H * HID) * IN * 2);
    int* src     = (int*)carve((size_t)ET * 4);
    int* dst     = (int*)carve((size_t)ET * 4);
    int* counts  = (int*)carve((size_t)N * 4);
    int* cursor  = (int*)carve((size_t)N * 4);
    int* offsets = (int*)carve((size_t)(N + 1) * 4);
    int* esrc    = (int*)carve((size_t)ET * 4);
    // aliases
    unsigned short* h1_h = x_hi;
    unsigned short* h1_l = x_hi + (size_t)M2 * HID;
    unsigned short* xlr2 = xlr1;
    unsigned short* BT2  = BT1;

    // ---- CSR build ----
    hipMemsetAsync(counts, 0, (size_t)((char*)offsets - (char*)counts), stream);
    build_edges<<<(ET + 255) / 256, 256, 0, stream>>>(ei, E, N, src, dst, counts);
    scan_offsets<<<1, 1024, 0, stream>>>(counts, offsets, N);
    fill_eids<<<(ET + 255) / 256, 256, 0, stream>>>(src, dst, offsets, cursor, esrc, ET);

    // ---- prep layer 1 ----
    {
        int total4 = M2 * IN / 4;
        conv_hi<<<(total4 + 255) / 256, 256, 0, stream>>>(x, x_hi, N, 9, total4);
        thi<<<dim3((H * HID) / 32, IN / 32), dim3(32, 8), 0, stream>>>(Wl1, BT1, IN, H * HID);
        thi<<<dim3((H * HID) / 32, IN / 32), dim3(32, 8), 0, stream>>>(Wr1, BT1 + (size_t)(H * HID) * IN, IN, H * HID);
    }
    // ---- layer 1 GEMM (combined Wl|Wr, pure bf16, bf16 out): [M2][512]@[512][2048] ----
    {
        dim3 g((2 * H * HID) / 128, M2 / 128);
        gemm_mfma<1, true><<<g, 256, 0, stream>>>(x_hi, nullptr, BT1, nullptr, xlr1, N, 2 * H * HID, IN);
    }
    // ---- layer 1 aggregate (bf16 in) -> h1 split (padded) ----
    fused_agg<256, 0, true, 2048><<<M2, 256, 0, stream>>>(xlr1, xlr1 + H * HID, att1, offsets, esrc, b1,
                                                          nullptr, h1_h, h1_l, N);
    // ---- prep layer 2 ----
    thi<<<dim3((H * OUT) / 32, HID / 32), dim3(32, 8), 0, stream>>>(Wl2, BT2, HID, H * OUT);
    thi<<<dim3((H * OUT) / 32, HID / 32), dim3(32, 8), 0, stream>>>(Wr2, BT2 + (size_t)(H * OUT) * HID, HID, H * OUT);
    // ---- layer 2 GEMM (combined, 2-term, bf16 out): [M2][256]@[256][1024] ----
    {
        dim3 g((2 * H * OUT) / 128, M2 / 128);
        gemm_mfma<2, true><<<g, 256, 0, stream>>>(h1_h, h1_l, BT2, nullptr, xlr2, N, 2 * H * OUT, HID);
    }
    // ---- layer 2 aggregate (bf16 in) -> out ----
    fused_agg<128, 1, false, 1024><<<N, 256, 0, stream>>>(xlr2, xlr2 + H * OUT, att2, offsets, esrc, b2,
                                                          out, nullptr, nullptr, N);
}